// Round 4
// baseline (10.178 us; speedup 1.0000x reference)
//
#include <hip/hip_runtime.h>
#include <math.h>

// Fused Net_6maxFull, round 4: phase-1 uses one-gate-per-lane + shuffle
// combine (short serial chain, max load parallelism), 3 barriers, 960 thr.

__device__ __forceinline__ float fsig(float v) {
    return __fdividef(1.0f, 1.0f + __expf(-v));
}
__device__ __forceinline__ float ftanh(float v) {
    return 1.0f - __fdividef(2.0f, 1.0f + __expf(2.0f * v));
}

__global__ __launch_bounds__(960) void net6max_kernel(
    const float* __restrict__ x,        // [37]
    const float* __restrict__ gen_Wih,  // [10][40][12]
    const float* __restrict__ gen_Whh,  // [10][40][10]
    const float* __restrict__ gen_bih,  // [10][40]
    const float* __restrict__ gen_bhh,  // [10][40]
    const float* __restrict__ gen_h0,   // [10][10]
    const float* __restrict__ gen_c0,   // [10][10]
    const float* __restrict__ game_Wih, // [5][10][20][4]
    const float* __restrict__ game_Whh, // [5][10][20][5]
    const float* __restrict__ game_bih, // [5][10][20]
    const float* __restrict__ game_bhh, // [5][10][20]
    const float* __restrict__ game_h0,  // [5][10][5]
    const float* __restrict__ game_c0,  // [5][10][5]
    const float* __restrict__ W1,       // [50][200]
    const float* __restrict__ b1,       // [50]
    const float* __restrict__ W2,       // [10][50]
    const float* __restrict__ b2,       // [10]
    const float* __restrict__ W3,       // [1][10]
    const float* __restrict__ b3,       // [1]
    float* __restrict__ out)            // [1]
{
    __shared__ __align__(16) float s_hgame[5][10][5];
    __shared__ __align__(16) float s_test[200];
    __shared__ __align__(16) float s_h1[52];

    const int tid = threadIdx.x;

    // ======== Phase 1a: gen LSTM — one gate per lane, shuffle combine ====
    if (tid < 400) {
        int cell = tid >> 2, gq = tid & 3;       // cell = k*10+j
        int k = cell / 10, j = cell % 10;
        int r = gq * 10 + j;                     // gate row within [40]
        int row = k * 40 + r;
        const float4* w4 = (const float4*)(gen_Wih + (size_t)row * 12);
        const float2* u2 = (const float2*)(gen_Whh + (size_t)row * 10);
        const float2* h02 = (const float2*)(gen_h0 + k * 10);
        float4 xa = *(const float4*)&x[0];       // uniform
        float4 xb = *(const float4*)&x[4];
        float4 xc = *(const float4*)&x[8];
        float4 p = w4[0] * xa + w4[1] * xb + w4[2] * xc;
        float2 q = u2[0] * h02[0] + u2[1] * h02[1] + u2[2] * h02[2]
                 + u2[3] * h02[3] + u2[4] * h02[4];
        float gate = gen_bih[row] + gen_bhh[row]
                   + p.x + p.y + p.z + p.w + q.x + q.y;
        // nonlinearity: gq==2 -> tanh, else sigmoid (branchless)
        bool isg = (gq == 2);
        float a = isg ? 2.0f * gate : -gate;
        float D = __fdividef(1.0f, 1.0f + __expf(a));
        float v = isg ? 1.0f - 2.0f * D : D;     // v0=sig(i) v1=sig(f) v2=tanh(g) v3=sig(o)
        float c0v = gen_c0[cell];
        float w = __shfl_xor(v, 2);              // gq0<-v2, gq1<-v3
        float pp = (gq == 1) ? v * c0v : v * w;  // gq0: v0*v2 ; gq1: v1*c0
        float r1 = __shfl_xor(pp, 1);            // gq0 <- v1*c0
        float r2 = __shfl_xor(w, 1);             // gq0 <- v3
        if (gq == 0) {
            float c = pp + r1;
            s_test[cell] = ftanh(c) * r2;
        }
    } else if (tid >= 448 && tid < 948) {
        // ==== Phase 1b: game LSTM — two gates per lane, pair combine ====
        int u = tid - 448;
        int idx = u >> 1, q = u & 1;             // idx = o*50 + (k*5+j)
        int o = idx / 50;
        int rem = idx % 50;
        int k = rem / 5, j = rem % 5;
        int ok = o * 10 + k;
        // q=0: rows {j, 10+j} (i, g) ; q=1: rows {5+j, 15+j} (f, o)
        int rA = q * 5 + j;
        int rB = rA + 10;
        const float* Wk = game_Wih + (size_t)ok * 80;    // [20][4]
        const float* Uk = game_Whh + (size_t)ok * 100;   // [20][5]
        const float* bi = game_bih + ok * 20;
        const float* bh = game_bhh + ok * 20;
        const float* h0 = game_h0 + ok * 5;
        float h00 = h0[0], h01 = h0[1], h02_ = h0[2], h03 = h0[3], h04 = h0[4];
        const float* fx = x + 13 + 5 * o;
        float f0 = fx[0], f1 = fx[1], f2 = fx[2], f3 = fx[3];
        float4 wA = *(const float4*)(Wk + rA * 4);
        float4 wB = *(const float4*)(Wk + rB * 4);
        const float* uA = Uk + rA * 5;
        const float* uB = Uk + rB * 5;
        float gA = bi[rA] + bh[rA] + wA.x*f0 + wA.y*f1 + wA.z*f2 + wA.w*f3
                 + uA[0]*h00 + uA[1]*h01 + uA[2]*h02_ + uA[3]*h03 + uA[4]*h04;
        float gB = bi[rB] + bh[rB] + wB.x*f0 + wB.y*f1 + wB.z*f2 + wB.w*f3
                 + uB[0]*h00 + uB[1]*h01 + uB[2]*h02_ + uB[3]*h03 + uB[4]*h04;
        float vA = fsig(gA);                     // q0: sig(i) ; q1: sig(f)
        float vB = q ? fsig(gB) : ftanh(gB);     // q0: tanh(g); q1: sig(o)
        float c0v = game_c0[ok * 5 + j];
        float a = q ? vA * c0v : vA * vB;        // q0: i*g ; q1: f*c0
        float s1 = __shfl_xor(a, 1);             // q0 <- f*c0
        float s2 = __shfl_xor(vB, 1);            // q0 <- sig(o)
        if (q == 0) {
            float c = a + s1;
            s_hgame[o][k][j] = ftanh(c) * s2;
        }
    }
    __syncthreads();

    // ============ Phase 2: masked average -> test[100..199] ============
    if (tid < 100) {
        float msum = 0.0f, acc = 0.0f;
        #pragma unroll
        for (int o = 0; o < 5; ++o) {
            float m = (x[12 + 5 * o] == 1.0f) ? 1.0f : 0.0f;  // uniform
            msum += m;
            float v = (tid < 50) ? s_hgame[o][tid / 5][tid % 5]
                                 : s_hgame[o][9][tid % 5];
            acc += m * v;
        }
        s_test[100 + tid] = __fdividef(acc, msum);
    }
    __syncthreads();

    // ============ Phase 3: MLP layer 1 (50x200), 4 threads/row ============
    if (tid < 200) {
        int r = tid >> 2, q = tid & 3;
        const float4* w4 = (const float4*)(W1 + (size_t)r * 200);
        const float4* t4 = (const float4*)s_test;
        float4 acc4 = make_float4(0.f, 0.f, 0.f, 0.f);
        #pragma unroll
        for (int m = 0; m < 12; ++m) {
            int c4 = q + 4 * m;
            acc4 += w4[c4] * t4[c4];
        }
        if (q < 2) {
            int c4 = 48 + q;
            acc4 += w4[c4] * t4[c4];
        }
        float acc = acc4.x + acc4.y + acc4.z + acc4.w;
        acc += __shfl_xor(acc, 1);
        acc += __shfl_xor(acc, 2);
        if (q == 0) s_h1[r] = ftanh(acc + b1[r]);
    }
    __syncthreads();

    // ===== Phase 4: layers 2+3 fused in wave 0 =====
    if (tid < 32) {
        float acc = 0.f;
        if (tid < 20) {
            int r = tid >> 1, q = tid & 1;
            const float2* w2 = (const float2*)(W2 + (size_t)r * 50);
            const float2* h1v = (const float2*)s_h1;
            float2 acc2 = make_float2(0.f, 0.f);
            #pragma unroll
            for (int m = 0; m < 12; ++m) {
                int c = q + 2 * m;
                acc2 += w2[c] * h1v[c];
            }
            if (q == 0) acc2 += w2[24] * h1v[24];
            float a = acc2.x + acc2.y;
            a += __shfl_xor(a, 1);
            acc = (q == 0) ? ftanh(a + b2[r]) * W3[r] : 0.f;
        }
        acc += __shfl_xor(acc, 2);
        acc += __shfl_xor(acc, 4);
        acc += __shfl_xor(acc, 8);
        acc += __shfl_xor(acc, 16);
        acc += __shfl_xor(acc, 1);
        if (tid == 0) out[0] = ftanh(acc + b3[0]);
    }
}

extern "C" void kernel_launch(void* const* d_in, const int* in_sizes, int n_in,
                              void* d_out, int out_size, void* d_ws, size_t ws_size,
                              hipStream_t stream) {
    (void)in_sizes; (void)n_in; (void)out_size; (void)d_ws; (void)ws_size;
    const float* x        = (const float*)d_in[0];
    const float* gen_Wih  = (const float*)d_in[1];
    const float* gen_Whh  = (const float*)d_in[2];
    const float* gen_bih  = (const float*)d_in[3];
    const float* gen_bhh  = (const float*)d_in[4];
    const float* gen_h0   = (const float*)d_in[5];
    const float* gen_c0   = (const float*)d_in[6];
    const float* game_Wih = (const float*)d_in[7];
    const float* game_Whh = (const float*)d_in[8];
    const float* game_bih = (const float*)d_in[9];
    const float* game_bhh = (const float*)d_in[10];
    const float* game_h0  = (const float*)d_in[11];
    const float* game_c0  = (const float*)d_in[12];
    const float* W1       = (const float*)d_in[13];
    const float* b1       = (const float*)d_in[14];
    const float* W2       = (const float*)d_in[15];
    const float* b2       = (const float*)d_in[16];
    const float* W3       = (const float*)d_in[17];
    const float* b3       = (const float*)d_in[18];
    float* out = (float*)d_out;

    net6max_kernel<<<1, 960, 0, stream>>>(
        x, gen_Wih, gen_Whh, gen_bih, gen_bhh, gen_h0, gen_c0,
        game_Wih, game_Whh, game_bih, game_bhh, game_h0, game_c0,
        W1, b1, W2, b2, W3, b3, out);
}

// Round 6
// 9.986 us; speedup vs baseline: 1.0192x; 1.0192x over previous
//
#include <hip/hip_runtime.h>
#include <math.h>

// Fused Net_6maxFull, round 6: R5 structure with the W2-prefetch bug fixed
// (24 threads now cover all 250 float2 elements). 4 barriers, 1024 threads.

__device__ __forceinline__ float fsig(float v) {
    return __fdividef(1.0f, 1.0f + __expf(-v));
}
__device__ __forceinline__ float ftanh(float v) {
    return 1.0f - __fdividef(2.0f, 1.0f + __expf(2.0f * v));
}

__global__ __launch_bounds__(1024) void net6max_kernel(
    const float* __restrict__ x,        // [37]
    const float* __restrict__ gen_Wih,  // [10][40][12]
    const float* __restrict__ gen_Whh,  // [10][40][10]
    const float* __restrict__ gen_bih,  // [10][40]
    const float* __restrict__ gen_bhh,  // [10][40]
    const float* __restrict__ gen_h0,   // [10][10]
    const float* __restrict__ gen_c0,   // [10][10]
    const float* __restrict__ game_Wih, // [5][10][20][4]
    const float* __restrict__ game_Whh, // [5][10][20][5]
    const float* __restrict__ game_bih, // [5][10][20]
    const float* __restrict__ game_bhh, // [5][10][20]
    const float* __restrict__ game_h0,  // [5][10][5]
    const float* __restrict__ game_c0,  // [5][10][5]
    const float* __restrict__ W1,       // [50][200]
    const float* __restrict__ b1,       // [50]
    const float* __restrict__ W2,       // [10][50]
    const float* __restrict__ b2,       // [10]
    const float* __restrict__ W3,       // [1][10]
    const float* __restrict__ b3,       // [1]
    float* __restrict__ out)            // [1]
{
    // W1 staged with padded row stride 51 float4 (204 floats): 2-way banks (free)
    __shared__ __align__(16) float4 s_W1v[50 * 51];
    __shared__ __align__(16) float2 s_W2v[10 * 25];
    __shared__ __align__(16) float s_gates_g[400];
    __shared__ __align__(16) float s_gates_o[1000];
    __shared__ __align__(16) float s_hgame[5][10][5];
    __shared__ __align__(16) float s_test[200];
    __shared__ __align__(16) float s_h1[52];

    const int tid = threadIdx.x;

    // ======== Phase 1: all gates (one per thread), x via uniform loads ====
    if (tid < 400) {
        int k = tid / 40;
        const float4* wih4 = (const float4*)(gen_Wih + (size_t)tid * 12);
        const float2* whh2 = (const float2*)(gen_Whh + (size_t)tid * 10);
        const float2* h02  = (const float2*)(gen_h0 + k * 10);
        float4 xa = *(const float4*)&x[0];      // uniform -> s_load
        float4 xb = *(const float4*)&x[4];
        float4 xc = *(const float4*)&x[8];
        float4 p4 = wih4[0] * xa + wih4[1] * xb + wih4[2] * xc;
        float2 q2 = whh2[0] * h02[0] + whh2[1] * h02[1] + whh2[2] * h02[2]
                  + whh2[3] * h02[3] + whh2[4] * h02[4];
        s_gates_g[tid] = gen_bih[tid] + gen_bhh[tid]
                       + p4.x + p4.y + p4.z + p4.w + q2.x + q2.y;
    }
    {
        // game gates: exactly-once mapping (tids 400..423 free for W2 fetch)
        int gt = -1;
        if (tid < 400)       gt = 600 + tid;     // tasks 600..999
        else if (tid >= 424) gt = tid - 424;     // tasks 0..599
        if (gt >= 0) {
            int o   = gt / 200;
            int ok_ = gt / 20;                   // o*10 + k
            const float4* wih4 = (const float4*)(game_Wih + (size_t)gt * 4);
            const float*  whh  = game_Whh + (size_t)gt * 5;
            const float*  h0   = game_h0 + ok_ * 5;
            const float*  fx   = x + 13 + 5 * o;
            float4 w = wih4[0];
            float acc = game_bih[gt] + game_bhh[gt]
                      + w.x * fx[0] + w.y * fx[1] + w.z * fx[2] + w.w * fx[3];
            acc += whh[0]*h0[0] + whh[1]*h0[1] + whh[2]*h0[2]
                 + whh[3]*h0[3] + whh[4]*h0[4];
            s_gates_o[gt] = acc;
        }
    }
    // ---- W1 prefetch -> LDS (issued after gate loads; overlaps P1-P3) ----
    {
        const float4* W1v = (const float4*)W1;
        #pragma unroll
        for (int t = 0; t < 3; ++t) {
            int i = tid + t * 1024;
            if (i < 2500) {
                int row = i / 50, c4 = i % 50;
                s_W1v[row * 51 + c4] = W1v[i];
            }
        }
    }
    // ---- W2 prefetch by idle threads 400..423 (250 float2 over 24 thr) ----
    if (tid >= 400 && tid < 424) {
        const float2* W2v = (const float2*)W2;
        #pragma unroll
        for (int t = 0; t < 11; ++t) {
            int i = (tid - 400) + 24 * t;
            if (i < 250) s_W2v[i] = W2v[i];
        }
    }
    __syncthreads();

    // ======== Phase 2: LSTM nonlinearities (separate waves) ========
    if (tid < 100) {
        int k = tid / 10, j = tid % 10;
        int base = k * 40;
        float gi = s_gates_g[base + j];
        float gf = s_gates_g[base + 10 + j];
        float gg = s_gates_g[base + 20 + j];
        float go = s_gates_g[base + 30 + j];
        float c = fsig(gf) * gen_c0[tid] + fsig(gi) * ftanh(gg);
        s_test[tid] = fsig(go) * ftanh(c);
    } else if (tid >= 512 && tid < 762) {
        int t = tid - 512;
        int o = t / 50;
        int rem = t % 50;
        int k = rem / 5, j = rem % 5;
        int base = (o * 10 + k) * 20;
        float gi = s_gates_o[base + j];
        float gf = s_gates_o[base + 5 + j];
        float gg = s_gates_o[base + 10 + j];
        float go = s_gates_o[base + 15 + j];
        float c = fsig(gf) * game_c0[(o * 10 + k) * 5 + j] + fsig(gi) * ftanh(gg);
        s_hgame[o][k][j] = fsig(go) * ftanh(c);
    }
    __syncthreads();

    // ======== Phase 3: masked average -> test[100..199] ========
    if (tid < 100) {
        float msum = 0.0f, acc = 0.0f;
        #pragma unroll
        for (int o = 0; o < 5; ++o) {
            float m = (x[12 + 5 * o] == 1.0f) ? 1.0f : 0.0f;   // uniform
            msum += m;
            float v = (tid < 50) ? s_hgame[o][tid / 5][tid % 5]
                                 : s_hgame[o][9][tid % 5];
            acc += m * v;
        }
        s_test[100 + tid] = __fdividef(acc, msum);
    }
    __syncthreads();

    // ======== Phase 4: MLP layer 1 (50x200) from LDS, 4 thr/row ========
    if (tid < 200) {
        int r = tid >> 2, q = tid & 3;
        const float4* w4 = &s_W1v[r * 51];
        const float4* t4 = (const float4*)s_test;
        float4 acc4 = make_float4(0.f, 0.f, 0.f, 0.f);
        #pragma unroll
        for (int m = 0; m < 12; ++m) {
            int c4 = q + 4 * m;
            acc4 += w4[c4] * t4[c4];
        }
        if (q < 2) {
            int c4 = 48 + q;
            acc4 += w4[c4] * t4[c4];
        }
        float acc = acc4.x + acc4.y + acc4.z + acc4.w;
        acc += __shfl_xor(acc, 1);
        acc += __shfl_xor(acc, 2);
        if (q == 0) s_h1[r] = ftanh(acc + b1[r]);
    }
    __syncthreads();

    // ======== Phase 5: layers 2+3 fused in wave 0 ========
    if (tid < 32) {
        float acc = 0.f;
        if (tid < 20) {
            int r = tid >> 1, q = tid & 1;
            const float2* w2 = &s_W2v[r * 25];
            const float2* h1v = (const float2*)s_h1;
            float2 acc2 = make_float2(0.f, 0.f);
            #pragma unroll
            for (int m = 0; m < 12; ++m) {
                int c = q + 2 * m;
                acc2 += w2[c] * h1v[c];
            }
            if (q == 0) acc2 += w2[24] * h1v[24];
            float a = acc2.x + acc2.y;
            a += __shfl_xor(a, 1);
            acc = (q == 0) ? ftanh(a + b2[r]) * W3[r] : 0.f;
        }
        acc += __shfl_xor(acc, 2);
        acc += __shfl_xor(acc, 4);
        acc += __shfl_xor(acc, 8);
        acc += __shfl_xor(acc, 16);
        acc += __shfl_xor(acc, 1);
        if (tid == 0) out[0] = ftanh(acc + b3[0]);
    }
}

extern "C" void kernel_launch(void* const* d_in, const int* in_sizes, int n_in,
                              void* d_out, int out_size, void* d_ws, size_t ws_size,
                              hipStream_t stream) {
    (void)in_sizes; (void)n_in; (void)out_size; (void)d_ws; (void)ws_size;
    const float* x        = (const float*)d_in[0];
    const float* gen_Wih  = (const float*)d_in[1];
    const float* gen_Whh  = (const float*)d_in[2];
    const float* gen_bih  = (const float*)d_in[3];
    const float* gen_bhh  = (const float*)d_in[4];
    const float* gen_h0   = (const float*)d_in[5];
    const float* gen_c0   = (const float*)d_in[6];
    const float* game_Wih = (const float*)d_in[7];
    const float* game_Whh = (const float*)d_in[8];
    const float* game_bih = (const float*)d_in[9];
    const float* game_bhh = (const float*)d_in[10];
    const float* game_h0  = (const float*)d_in[11];
    const float* game_c0  = (const float*)d_in[12];
    const float* W1       = (const float*)d_in[13];
    const float* b1       = (const float*)d_in[14];
    const float* W2       = (const float*)d_in[15];
    const float* b2       = (const float*)d_in[16];
    const float* W3       = (const float*)d_in[17];
    const float* b3       = (const float*)d_in[18];
    float* out = (float*)d_out;

    net6max_kernel<<<1, 1024, 0, stream>>>(
        x, gen_Wih, gen_Whh, gen_bih, gen_bhh, gen_h0, gen_c0,
        game_Wih, game_Whh, game_bih, game_bhh, game_h0, game_c0,
        W1, b1, W2, b2, W3, b3, out);
}